// Round 1
// baseline (262.428 us; speedup 1.0000x reference)
//
#include <hip/hip_runtime.h>
#include <stdint.h>

// ---------------- problem constants ----------------
#define TT 262144
#define KK 32
#define DD 64
#define LSTEP 64               // scan steps per chunk
#define PCH 4096               // chunks (covers transitions t=1..T-1; last chunk has 63 steps)
#define G2 64                  // chunks combined per k2 wave
#define NW2 (PCH / G2)         // 64 group matrices for k3

typedef __attribute__((ext_vector_type(4)))  float f4v;
typedef __attribute__((ext_vector_type(16))) float f16v;
typedef __attribute__((ext_vector_type(4)))  short s4v;
typedef __attribute__((ext_vector_type(2)))  int   i2v;

// ---------------- ws layout ----------------
// ushort-unit offsets (region = float [0,2560))
#define WS_AFRAG_US 0          // ushort[1024] : Anorm^T A-frags [g:4][lane:64][e:4]
#define WS_WFRAG_US 1024       // ushort[4096] : W B-frags      [s:16][lane:64][e:4]
// float-unit offsets
#define WS_WF    2560          // float[4096]  : W fp32 [dd:128][k:32] (for k3 ll0)
#define WS_CK    6656          // float[32]
#define WS_AM1   6688          // float[32]
#define WS_BB    6720          // float[32]
#define WS_PI0   6752          // float[32]
#define WS_LS    8192          // float[PCH]   : chunk log-scales
#define WS_LS2   12288         // float[NW2]
#define WS_MATS  16384         // float[PCH*1024] : chunk matrices S_p = C_p^T (row-major 32x32)
#define WS_MATS2 (16384 + PCH*1024) // float[NW2*1024]
// total floats = 4276224  (~17.1 MB) -- assumes ws_size >= 18 MB

// pack two fp32 -> two bf16 (RTZ) in one dword: {hi[31:16], lo[31:16]}
__device__ __forceinline__ unsigned pkbf(float hi, float lo) {
    return __builtin_amdgcn_perm(__builtin_bit_cast(unsigned, hi),
                                 __builtin_bit_cast(unsigned, lo), 0x07060302u);
}
__device__ __forceinline__ unsigned short f2bf_rne(float f) {
    unsigned u = __builtin_bit_cast(unsigned, f);
    unsigned r = u + 0x7FFFu + ((u >> 16) & 1u);
    return (unsigned short)(r >> 16);
}
__device__ __forceinline__ float wmax32(float v) {
    v = fmaxf(v, __shfl_xor(v, 1));  v = fmaxf(v, __shfl_xor(v, 2));
    v = fmaxf(v, __shfl_xor(v, 4));  v = fmaxf(v, __shfl_xor(v, 8));
    v = fmaxf(v, __shfl_xor(v, 16));
    return v;
}
__device__ __forceinline__ float wmax64(float v) {
    v = wmax32(v); v = fmaxf(v, __shfl_xor(v, 32));
    return v;
}
__device__ __forceinline__ float wsum32(float v) {
    v += __shfl_xor(v, 1); v += __shfl_xor(v, 2); v += __shfl_xor(v, 4);
    v += __shfl_xor(v, 8); v += __shfl_xor(v, 16);
    return v;
}
__device__ __forceinline__ float wsum64(float v) {
    v = wsum32(v); v += __shfl_xor(v, 32);
    return v;
}
// feature-weight value: dd<64 -> -0.5*inv_var[k][dd]; dd>=64 -> mu*inv_var
__device__ __forceinline__ float wval(int dd, int k, const float* mu, const float* lsg) {
    int d = dd & 63;
    float lv = lsg[k * DD + d];
    float iv = __expf(-2.f * lv);
    return (dd < DD) ? (-0.5f * iv) : (mu[k * DD + d] * iv);
}

// ================= k0: constants / fragment preformat =================
__global__ void k0_prep(const float* __restrict__ Y, const float* __restrict__ A,
                        const float* __restrict__ lab, const float* __restrict__ mu,
                        const float* __restrict__ lsg, const float* __restrict__ pi,
                        float* __restrict__ ws, float* __restrict__ out)
{
    __shared__ float lseA[KK];
    const int tid = threadIdx.x;
    if (tid < KK) {
        float m = -1e30f;
        for (int j = 0; j < KK; ++j) m = fmaxf(m, A[tid * KK + j]);
        float s = 0.f;
        for (int j = 0; j < KK; ++j) s += __expf(A[tid * KK + j] - m);
        lseA[tid] = m + __logf(s);

        float mp = -1e30f;
        for (int j = 0; j < KK; ++j) mp = fmaxf(mp, pi[j]);
        float sp = 0.f;
        for (int j = 0; j < KK; ++j) sp += __expf(pi[j] - mp);
        ws[WS_PI0 + tid] = pi[tid] - (mp + __logf(sp));

        float la = lab[tid * 2 + 0], lb = lab[tid * 2 + 1];
        float a = __expf(la), b = __expf(lb);
        float c1 = 0.f, c2 = 0.f;
        for (int d = 0; d < DD; ++d) {
            float lv = lsg[tid * DD + d];
            float mv = mu[tid * DD + d];
            c1 -= lv;
            c2 += mv * mv * __expf(-2.f * lv);
        }
        ws[WS_CK + tid]  = a * lb - lgammaf(a) + c1 - 0.5f * c2 - 32.f * 1.8378770664093453f;
        ws[WS_AM1 + tid] = a - 1.f;
        ws[WS_BB + tid]  = b;
    }
    __syncthreads();
    unsigned short* us = (unsigned short*)ws;
    // Anorm^T A-frags: phase g, lane l holds A^T[i=l&31][m=8g+4*(l>>5)+e] = Anorm[m][i]
    for (int idx = tid; idx < 1024; idx += 256) {
        int g = idx >> 8, rem = idx & 255, ln = rem >> 2, e = rem & 3;
        int m = 8 * g + 4 * (ln >> 5) + e, i = ln & 31;
        us[WS_AFRAG_US + idx] = f2bf_rne(__expf(A[m * KK + i] - lseA[m]));
    }
    // W B-frags: phase s, lane l holds W[dd=8s+4*(l>>5)+e][k=l&31]
    for (int idx = tid; idx < 4096; idx += 256) {
        int s = idx >> 8, rem = idx & 255, ln = rem >> 2, e = rem & 3;
        int dd = 8 * s + 4 * (ln >> 5) + e, k = ln & 31;
        us[WS_WFRAG_US + idx] = f2bf_rne(wval(dd, k, mu, lsg));
    }
    for (int idx = tid; idx < 4096; idx += 256) {
        int dd = idx >> 5, k = idx & 31;
        ws[WS_WF + idx] = wval(dd, k, mu, lsg);
    }
    if (tid < DD) out[tid] = Y[tid];   // h row 0 (chunks cover rows 1..T-1)
}

// ================= k1: chunk scan (1 wave = 1 chunk of 64 steps) =================
__global__ __launch_bounds__(256, 4) void k1_scan(
    const float* __restrict__ Y, const float* __restrict__ dTp,
    float* __restrict__ ws, float* __restrict__ out)
{
    __shared__ unsigned short wfr[4096];
    __shared__ float E[4][32][32];
    __shared__ float dtv[4][32], dtl[4][32];

    const int tid = threadIdx.x;
    {
        const unsigned short* wsrc = (const unsigned short*)ws + WS_WFRAG_US;
        for (int i = tid; i < 4096; i += 256) wfr[i] = wsrc[i];
    }
    __syncthreads();

    const int wv = tid >> 6, l = tid & 63, h = l >> 5, c = l & 31;
    const int p = blockIdx.x * 4 + wv;
    const int t0 = 1 + p * LSTEP;                 // first transition handled by this chunk
    const int nsteps = min(LSTEP, TT - t0);       // 64, except 63 for the last chunk

    const unsigned short* afr = (const unsigned short*)ws + WS_AFRAG_US;
    s4v aF[4];
    #pragma unroll
    for (int g = 0; g < 4; ++g) aF[g] = *(const s4v*)(afr + g * 256 + l * 4);

    const float cK = ws[WS_CK + c], am1 = ws[WS_AM1 + c], bb = ws[WS_BB + c];

    f16v zf;
    #pragma unroll
    for (int r = 0; r < 16; ++r) zf[r] = 0.f;

    f16v S;   // S = C_p^T (scaled exp domain), C-layout: lane holds col c, rows 8m+4h+j
    #pragma unroll
    for (int m = 0; m < 4; ++m)
        #pragma unroll
        for (int j = 0; j < 4; ++j)
            S[4 * m + j] = ((8 * m + 4 * h + j) == c) ? 1.f : 0.f;

    float l2acc = 0.f;   // sum of log2(rescale factors)
    float cacc  = 0.f;   // sum of per-step c_t

    for (int tb = 0; tb < 2; ++tb) {
        const int trow = t0 + tb * 32 + c;
        const bool vld = trow < TT;

        if (l < 32) {
            int t = t0 + tb * 32 + l;
            float dv = (t < TT) ? dTp[t] : 1.f;
            dtv[wv][l] = dv;
            dtl[wv][l] = __logf(dv);
        }

        // ---- emission ll tile via MFMA (A=[Y^2,Y] features, B=W), fused Y->h copy ----
        f16v acc = zf;
        s4v rawf[8];
        const float* yrow = Y + (size_t)trow * DD;
        float* orow = out + (size_t)trow * DD;
        #pragma unroll
        for (int g = 0; g < 8; ++g) {
            const int col = 8 * g + 4 * h;
            f4v y4; y4[0] = 0.f; y4[1] = 0.f; y4[2] = 0.f; y4[3] = 0.f;
            if (vld) y4 = *(const f4v*)(yrow + col);
            if (vld) *(f4v*)(orow + col) = y4;
            f4v q4 = y4 * y4;
            i2v sq; sq[0] = pkbf(q4[1], q4[0]); sq[1] = pkbf(q4[3], q4[2]);
            i2v rw; rw[0] = pkbf(y4[1], y4[0]); rw[1] = pkbf(y4[3], y4[2]);
            rawf[g] = __builtin_bit_cast(s4v, rw);
            s4v wf = *(const s4v*)(wfr + g * 256 + l * 4);
            acc = __builtin_amdgcn_mfma_f32_32x32x8bf16_1k(__builtin_bit_cast(s4v, sq), wf, acc, 0, 0, 0);
        }
        #pragma unroll
        for (int g = 0; g < 8; ++g) {
            s4v wf = *(const s4v*)(wfr + (8 + g) * 256 + l * 4);
            acc = __builtin_amdgcn_mfma_f32_32x32x8bf16_1k(rawf[g], wf, acc, 0, 0, 0);
        }

        asm volatile("s_waitcnt lgkmcnt(0)" ::: "memory");  // dtv/dtl visible

        // ---- ll -> c_t (row max), e = exp(ll-c) into E ----
        float csv = 0.f;
        #pragma unroll
        for (int m = 0; m < 4; ++m) {
            const f4v dv4 = *(const f4v*)(&dtv[wv][8 * m + 4 * h]);
            const f4v dl4 = *(const f4v*)(&dtl[wv][8 * m + 4 * h]);
            #pragma unroll
            for (int j = 0; j < 4; ++j) {
                const int row = 8 * m + 4 * h + j;
                float llv = acc[4 * m + j] + cK + am1 * dl4[j] - bb * dv4[j];
                float cm = wmax32(llv);          // max over k (lanes within half share the row)
                E[wv][row][c] = __expf(llv - cm);
                csv += ((tb * 32 + row) < nsteps) ? cm : 0.f;
            }
        }
        cacc += wsum64(csv) * (1.f / 32.f);      // each row's c duplicated over 32 lanes

        asm volatile("s_waitcnt lgkmcnt(0)" ::: "memory");  // E visible

        // ---- scan: S <- diag(e_t) * Anorm^T * S ----
        int ns = nsteps - tb * 32;
        ns = ns < 0 ? 0 : (ns > 32 ? 32 : ns);
        for (int n = 0; n < ns; ++n) {
            f16v Dv = zf;
            #pragma unroll
            for (int g = 0; g < 4; ++g) {
                // K=8 MFMA: B-frag rows 8g+4h+{0..3} == C-layout regs 4g+{0..3}; no shuffle!
                i2v bd; bd[0] = pkbf(S[4 * g + 1], S[4 * g + 0]);
                        bd[1] = pkbf(S[4 * g + 3], S[4 * g + 2]);
                Dv = __builtin_amdgcn_mfma_f32_32x32x8bf16_1k(aF[g], __builtin_bit_cast(s4v, bd), Dv, 0, 0, 0);
            }
            const f4v* erow = (const f4v*)(&E[wv][n][0]);
            #pragma unroll
            for (int m = 0; m < 4; ++m) {
                const f4v e4 = erow[2 * m + h];  // e for output rows 8m+4h+{0..3}
                #pragma unroll
                for (int j = 0; j < 4; ++j) S[4 * m + j] = Dv[4 * m + j] * e4[j];
            }
            if ((n & 3) == 3) {                  // rescale (worst-case decay ~e^-13/step)
                float mx = S[0];
                #pragma unroll
                for (int r = 1; r < 16; ++r) mx = fmaxf(mx, S[r]);
                mx = wmax64(mx);
                const float inv = __fdividef(1.f, mx);
                #pragma unroll
                for (int r = 0; r < 16; ++r) S[r] *= inv;
                l2acc += __log2f(mx);
            }
        }
    }

    // ---- store chunk matrix + logscale ----
    float* mp = ws + WS_MATS + (size_t)p * 1024;
    #pragma unroll
    for (int m = 0; m < 4; ++m)
        #pragma unroll
        for (int j = 0; j < 4; ++j)
            mp[(8 * m + 4 * h + j) * 32 + c] = S[4 * m + j];
    if (l == 0) ws[WS_LS + p] = cacc + 0.69314718055994531f * l2acc;
}

// ================= k2: combine 64 consecutive chunk matrices per wave =================
__global__ __launch_bounds__(64) void k2_combine(float* __restrict__ ws)
{
    const int l = threadIdx.x, h = l >> 5, c = l & 31;
    const int w = blockIdx.x;
    const int m0 = w * G2;
    const float* mats = ws + WS_MATS;
    f16v zf;
    #pragma unroll
    for (int r = 0; r < 16; ++r) zf[r] = 0.f;
    f16v U;
    #pragma unroll
    for (int m = 0; m < 4; ++m)
        #pragma unroll
        for (int j = 0; j < 4; ++j)
            U[4 * m + j] = mats[(size_t)m0 * 1024 + (8 * m + 4 * h + j) * 32 + c];
    float lacc = 0.f;
    float lssum = ws[WS_LS + m0];
    f4v pf[4];
    {
        const float* bq = mats + (size_t)(m0 + 1) * 1024 + c * 32;
        #pragma unroll
        for (int g = 0; g < 4; ++g) pf[g] = *(const f4v*)(bq + 8 * g + 4 * h);
    }
    for (int q = 1; q < G2; ++q) {
        f4v cur[4];
        #pragma unroll
        for (int g = 0; g < 4; ++g) cur[g] = pf[g];
        const float lsq = ws[WS_LS + m0 + q];
        if (q + 1 < G2) {   // prefetch next matrix (A-side rows: lane reads row i=c)
            const float* bq = mats + (size_t)(m0 + q + 1) * 1024 + c * 32;
            #pragma unroll
            for (int g = 0; g < 4; ++g) pf[g] = *(const f4v*)(bq + 8 * g + 4 * h);
        }
        f16v Dv = zf;
        #pragma unroll
        for (int g = 0; g < 4; ++g) {   // U <- S_q * U
            i2v ad; ad[0] = pkbf(cur[g][1], cur[g][0]); ad[1] = pkbf(cur[g][3], cur[g][2]);
            i2v bd; bd[0] = pkbf(U[4 * g + 1], U[4 * g + 0]); bd[1] = pkbf(U[4 * g + 3], U[4 * g + 2]);
            Dv = __builtin_amdgcn_mfma_f32_32x32x8bf16_1k(
                __builtin_bit_cast(s4v, ad), __builtin_bit_cast(s4v, bd), Dv, 0, 0, 0);
        }
        float mx = Dv[0];
        #pragma unroll
        for (int r = 1; r < 16; ++r) mx = fmaxf(mx, Dv[r]);
        mx = wmax64(mx);
        const float inv = __fdividef(1.f, mx);
        #pragma unroll
        for (int r = 0; r < 16; ++r) U[r] = Dv[r] * inv;
        lacc += __log2f(mx);
        lssum += lsq;
    }
    float* m2 = ws + WS_MATS2 + (size_t)w * 1024;
    #pragma unroll
    for (int m = 0; m < 4; ++m)
        #pragma unroll
        for (int j = 0; j < 4; ++j)
            m2[(8 * m + 4 * h + j) * 32 + c] = U[4 * m + j];
    if (l == 0) ws[WS_LS2 + w] = lssum + 0.69314718055994531f * lacc;
}

// ================= k3: alpha0 + final vector chain + loss =================
__global__ __launch_bounds__(64) void k3_final(
    const float* __restrict__ Y, const float* __restrict__ dTp,
    float* __restrict__ ws, float* __restrict__ out)
{
    __shared__ float ab[KK];
    const int l = threadIdx.x, h = l >> 5, c = l & 31;

    // ll[0][k] for k=c (lanes duplicated across halves)
    float acc = 0.f;
    const float* Wf = ws + WS_WF;
    for (int dd = 0; dd < 128; ++dd) {
        const float yv = Y[dd & 63];
        const float f = (dd < 64) ? yv * yv : yv;
        acc = fmaf(f, Wf[dd * 32 + c], acc);
    }
    const float dt0 = dTp[0];
    const float ll0 = acc + ws[WS_CK + c] + ws[WS_AM1 + c] * __logf(dt0) - ws[WS_BB + c] * dt0;
    const float av = ws[WS_PI0 + c] + ll0;
    const float c0 = wmax32(av);
    float anew = __expf(av - c0);
    float lstot = c0;
    if (l < 32) ab[c] = anew;
    asm volatile("s_waitcnt lgkmcnt(0)" ::: "memory");

    const float* m2 = ws + WS_MATS2;
    f4v pf[4];
    {
        const float* r0 = m2 + c * 32 + 16 * h;
        #pragma unroll
        for (int i = 0; i < 4; ++i) pf[i] = *(const f4v*)(r0 + 4 * i);
    }
    for (int g = 0; g < NW2; ++g) {
        f4v cur[4];
        #pragma unroll
        for (int i = 0; i < 4; ++i) cur[i] = pf[i];
        const float lsg = ws[WS_LS2 + g];
        if (g + 1 < NW2) {
            const float* rn = m2 + (size_t)(g + 1) * 1024 + c * 32 + 16 * h;
            #pragma unroll
            for (int i = 0; i < 4; ++i) pf[i] = *(const f4v*)(rn + 4 * i);
        }
        // a_new[j=c] = sum_i U_g[j][i]*a[i]; halves split the i-range
        float part = 0.f;
        #pragma unroll
        for (int i = 0; i < 4; ++i) {
            const f4v a4 = *(const f4v*)(&ab[16 * h + 4 * i]);
            part = fmaf(cur[i][0], a4[0], part);
            part = fmaf(cur[i][1], a4[1], part);
            part = fmaf(cur[i][2], a4[2], part);
            part = fmaf(cur[i][3], a4[3], part);
        }
        const float s = part + __shfl_xor(part, 32);
        const float mx = wmax32(s);
        lstot += __logf(mx) + lsg;
        anew = __fdividef(s, mx);
        asm volatile("" ::: "memory");
        if (l < 32) ab[c] = anew;
        asm volatile("s_waitcnt lgkmcnt(0)" ::: "memory");
    }
    const float ssum = wsum32(anew);
    if (l == 0) out[(size_t)TT * DD] = -(lstot + __logf(ssum));
}

// ================= launcher =================
extern "C" void kernel_launch(void* const* d_in, const int* in_sizes, int n_in,
                              void* d_out, int out_size, void* d_ws, size_t ws_size,
                              hipStream_t stream)
{
    const float* Y   = (const float*)d_in[0];
    const float* dTp = (const float*)d_in[1];
    const float* A   = (const float*)d_in[2];
    const float* lab = (const float*)d_in[3];
    const float* mu  = (const float*)d_in[4];
    const float* lsg = (const float*)d_in[5];
    const float* pi  = (const float*)d_in[6];
    float* out = (float*)d_out;
    float* ws  = (float*)d_ws;

    hipLaunchKernelGGL(k0_prep, dim3(1), dim3(256), 0, stream, Y, A, lab, mu, lsg, pi, ws, out);
    hipLaunchKernelGGL(k1_scan, dim3(PCH / 4), dim3(256), 0, stream, Y, dTp, ws, out);
    hipLaunchKernelGGL(k2_combine, dim3(NW2), dim3(64), 0, stream, ws);
    hipLaunchKernelGGL(k3_final, dim3(1), dim3(64), 0, stream, Y, dTp, ws, out);
}

// Round 2
// 213.728 us; speedup vs baseline: 1.2279x; 1.2279x over previous
//
#include <hip/hip_runtime.h>
#include <stdint.h>

// ---------------- problem constants ----------------
#define TT 262144
#define KK 32
#define DD 64
#define LSTEP 32               // scan steps per chunk
#define PCH 8192               // chunks (transitions t=1..T-1; last chunk has 31 steps)

typedef __attribute__((ext_vector_type(4)))  float f4v;
typedef __attribute__((ext_vector_type(16))) float f16v;
typedef __attribute__((ext_vector_type(4)))  short s4v;
typedef __attribute__((ext_vector_type(2)))  int   i2v;
typedef __attribute__((ext_vector_type(2)))  unsigned int u2v;
typedef __attribute__((ext_vector_type(4)))  unsigned int u4v;

// ---------------- ws layout ----------------
// ushort-unit offsets (prep region)
#define WS_AFRAG_US 0          // ushort[1024] : Anorm^T A-frags [g:4][lane:64][e:4]
#define WS_WFRAG_US 1024       // ushort[4096] : W B-frags      [s:16][lane:64][e:4]
// float-unit offsets
#define WS_WF    2560          // float[4096]  : W fp32 [dd:128][k:32] (for k3 ll0)
#define WS_CK    6656          // float[32]
#define WS_AM1   6688          // float[32]
#define WS_BB    6720          // float[32]
#define WS_PI0   6752          // float[32]
#define WS_LS    8192          // float[PCH]   : chunk log-scales
#define WS_LS2   16384         // float[128]   : group log-scales
// short-unit offsets (matrix storage, bf16)
#define SH_MATS  33280                  // ushort[PCH*1024]  : chunk mats, A-frag order
#define SH_MATS2 (33280 + PCH*1024)     // ushort[128*1024]  : group mats, A-frag order
#define LN2F 0.69314718055994531f

__device__ __forceinline__ unsigned pkbf(float hi, float lo) {
    return __builtin_amdgcn_perm(__builtin_bit_cast(unsigned, hi),
                                 __builtin_bit_cast(unsigned, lo), 0x07060302u);
}
__device__ __forceinline__ unsigned short f2bf_rne(float f) {
    unsigned u = __builtin_bit_cast(unsigned, f);
    unsigned r = u + 0x7FFFu + ((u >> 16) & 1u);
    return (unsigned short)(r >> 16);
}
__device__ __forceinline__ float bf2f(unsigned short u) {
    return __builtin_bit_cast(float, (unsigned)u << 16);
}
__device__ __forceinline__ float wmax32(float v) {
    v = fmaxf(v, __shfl_xor(v, 1));  v = fmaxf(v, __shfl_xor(v, 2));
    v = fmaxf(v, __shfl_xor(v, 4));  v = fmaxf(v, __shfl_xor(v, 8));
    v = fmaxf(v, __shfl_xor(v, 16));
    return v;
}
__device__ __forceinline__ float wmax64(float v) {
    v = wmax32(v); v = fmaxf(v, __shfl_xor(v, 32));
    return v;
}
__device__ __forceinline__ float wsum32(float v) {
    v += __shfl_xor(v, 1); v += __shfl_xor(v, 2); v += __shfl_xor(v, 4);
    v += __shfl_xor(v, 8); v += __shfl_xor(v, 16);
    return v;
}
__device__ __forceinline__ float wsum64(float v) {
    v = wsum32(v); v += __shfl_xor(v, 32);
    return v;
}
__device__ __forceinline__ float wval(int dd, int k, const float* mu, const float* lsg) {
    int d = dd & 63;
    float lv = lsg[k * DD + d];
    float iv = __expf(-2.f * lv);
    return (dd < DD) ? (-0.5f * iv) : (mu[k * DD + d] * iv);
}

// ================= k0: constants / fragment preformat =================
__global__ void k0_prep(const float* __restrict__ Y, const float* __restrict__ A,
                        const float* __restrict__ lab, const float* __restrict__ mu,
                        const float* __restrict__ lsg, const float* __restrict__ pi,
                        float* __restrict__ ws, float* __restrict__ out)
{
    __shared__ float lseA[KK];
    const int tid = threadIdx.x;
    if (tid < KK) {
        float m = -1e30f;
        for (int j = 0; j < KK; ++j) m = fmaxf(m, A[tid * KK + j]);
        float s = 0.f;
        for (int j = 0; j < KK; ++j) s += __expf(A[tid * KK + j] - m);
        lseA[tid] = m + __logf(s);

        float mp = -1e30f;
        for (int j = 0; j < KK; ++j) mp = fmaxf(mp, pi[j]);
        float sp = 0.f;
        for (int j = 0; j < KK; ++j) sp += __expf(pi[j] - mp);
        ws[WS_PI0 + tid] = pi[tid] - (mp + __logf(sp));

        float la = lab[tid * 2 + 0], lb = lab[tid * 2 + 1];
        float a = __expf(la), b = __expf(lb);
        float c1 = 0.f, c2 = 0.f;
        for (int d = 0; d < DD; ++d) {
            float lv = lsg[tid * DD + d];
            float mv = mu[tid * DD + d];
            c1 -= lv;
            c2 += mv * mv * __expf(-2.f * lv);
        }
        ws[WS_CK + tid]  = a * lb - lgammaf(a) + c1 - 0.5f * c2 - 32.f * 1.8378770664093453f;
        ws[WS_AM1 + tid] = a - 1.f;
        ws[WS_BB + tid]  = b;
    }
    __syncthreads();
    unsigned short* us = (unsigned short*)ws;
    for (int idx = tid; idx < 1024; idx += 256) {
        int g = idx >> 8, rem = idx & 255, ln = rem >> 2, e = rem & 3;
        int m = 8 * g + 4 * (ln >> 5) + e, i = ln & 31;
        us[WS_AFRAG_US + idx] = f2bf_rne(__expf(A[m * KK + i] - lseA[m]));
    }
    for (int idx = tid; idx < 4096; idx += 256) {
        int s = idx >> 8, rem = idx & 255, ln = rem >> 2, e = rem & 3;
        int dd = 8 * s + 4 * (ln >> 5) + e, k = ln & 31;
        us[WS_WFRAG_US + idx] = f2bf_rne(wval(dd, k, mu, lsg));
    }
    for (int idx = tid; idx < 4096; idx += 256) {
        int dd = idx >> 5, k = idx & 31;
        ws[WS_WF + idx] = wval(dd, k, mu, lsg);
    }
    if (tid < DD) out[tid] = Y[tid];   // h row 0
}

// ================= k1: chunk scan (1 wave = 1 chunk of 32 steps) =================
__global__ __launch_bounds__(256, 6) void k1_scan(
    const float* __restrict__ Y, const float* __restrict__ dTp,
    float* __restrict__ ws, float* __restrict__ out)
{
    __shared__ __align__(16) float E[4][32][32];     // per-wave; aliased as transpose buf at end
    __shared__ __align__(16) float dtv[4][32], dtl[4][32];

    const int tid = threadIdx.x;
    const int wv = tid >> 6, l = tid & 63, h = l >> 5, c = l & 31;
    const int p = blockIdx.x * 4 + wv;
    const int t0 = 1 + p * LSTEP;
    const int nsteps = min(LSTEP, TT - t0);

    const unsigned short* afr = (const unsigned short*)ws + WS_AFRAG_US;
    const unsigned short* wfr = (const unsigned short*)ws + WS_WFRAG_US;

    const float cK = ws[WS_CK + c], am1 = ws[WS_AM1 + c], bb = ws[WS_BB + c];

    if (l < 32) {
        int t = t0 + l;
        float dv = (t < TT) ? dTp[t] : 1.f;
        dtv[wv][l] = dv;
        dtl[wv][l] = __logf(dv);
    }

    f16v zf;
    #pragma unroll
    for (int r = 0; r < 16; ++r) zf[r] = 0.f;

    // ---- emission ll tile via MFMA, fused Y->h copy ----
    f16v acc = zf;
    s4v rawf[8];
    const int trow = t0 + c;
    const bool vld = trow < TT;
    const float* yrow = Y + (size_t)trow * DD;
    float* orow = out + (size_t)trow * DD;
    #pragma unroll
    for (int g = 0; g < 8; ++g) {
        const int col = 8 * g + 4 * h;
        f4v y4; y4[0] = 0.f; y4[1] = 0.f; y4[2] = 0.f; y4[3] = 0.f;
        if (vld) y4 = *(const f4v*)(yrow + col);
        if (vld) *(f4v*)(orow + col) = y4;
        f4v q4 = y4 * y4;
        i2v sq; sq[0] = pkbf(q4[1], q4[0]); sq[1] = pkbf(q4[3], q4[2]);
        i2v rw; rw[0] = pkbf(y4[1], y4[0]); rw[1] = pkbf(y4[3], y4[2]);
        rawf[g] = __builtin_bit_cast(s4v, rw);
        s4v wf = *(const s4v*)(wfr + g * 256 + l * 4);
        acc = __builtin_amdgcn_mfma_f32_32x32x8bf16_1k(__builtin_bit_cast(s4v, sq), wf, acc, 0, 0, 0);
    }
    #pragma unroll
    for (int g = 0; g < 8; ++g) {
        s4v wf = *(const s4v*)(wfr + (8 + g) * 256 + l * 4);
        acc = __builtin_amdgcn_mfma_f32_32x32x8bf16_1k(rawf[g], wf, acc, 0, 0, 0);
    }

    s4v aF[4];
    #pragma unroll
    for (int g = 0; g < 4; ++g) aF[g] = *(const s4v*)(afr + g * 256 + l * 4);

    asm volatile("s_waitcnt lgkmcnt(0)" ::: "memory");  // dtv/dtl visible

    // ---- ll -> c_t (row max over states), e = exp(ll-c) into E ----
    float csv = 0.f;
    #pragma unroll
    for (int m = 0; m < 4; ++m) {
        const f4v dv4 = *(const f4v*)(&dtv[wv][8 * m + 4 * h]);
        const f4v dl4 = *(const f4v*)(&dtl[wv][8 * m + 4 * h]);
        #pragma unroll
        for (int j = 0; j < 4; ++j) {
            const int row = 8 * m + 4 * h + j;
            float llv = acc[4 * m + j] + cK + am1 * dl4[j] - bb * dv4[j];
            float cm = wmax32(llv);
            E[wv][row][c] = __expf(llv - cm);
            csv += (row < nsteps) ? cm : 0.f;
        }
    }
    float cacc = wsum64(csv) * (1.f / 32.f);

    asm volatile("s_waitcnt lgkmcnt(0)" ::: "memory");  // E visible

    // ---- scan: S <- diag(e_t) * Anorm^T * S ----
    f16v S;
    #pragma unroll
    for (int m = 0; m < 4; ++m)
        #pragma unroll
        for (int j = 0; j < 4; ++j)
            S[4 * m + j] = ((8 * m + 4 * h + j) == c) ? 1.f : 0.f;
    float l2acc = 0.f;

    for (int n = 0; n < nsteps; ++n) {
        f16v Dv = zf;
        #pragma unroll
        for (int g = 0; g < 4; ++g) {
            i2v bd; bd[0] = pkbf(S[4 * g + 1], S[4 * g + 0]);
                    bd[1] = pkbf(S[4 * g + 3], S[4 * g + 2]);
            Dv = __builtin_amdgcn_mfma_f32_32x32x8bf16_1k(aF[g], __builtin_bit_cast(s4v, bd), Dv, 0, 0, 0);
        }
        const f4v* erow = (const f4v*)(&E[wv][n][0]);
        #pragma unroll
        for (int m = 0; m < 4; ++m) {
            const f4v e4 = erow[2 * m + h];
            #pragma unroll
            for (int j = 0; j < 4; ++j) S[4 * m + j] = Dv[4 * m + j] * e4[j];
        }
        if ((n & 3) == 3) {
            float mx = S[0];
            #pragma unroll
            for (int r = 1; r < 16; ++r) mx = fmaxf(mx, S[r]);
            mx = wmax64(mx);
            const float inv = __fdividef(1.f, mx);
            #pragma unroll
            for (int r = 0; r < 16; ++r) S[r] *= inv;
            l2acc += __log2f(mx);
        }
    }

    // ---- transpose S (C-layout) -> A-frag order bf16, store to global ----
    unsigned short* Tb = (unsigned short*)&E[wv][0][0];   // 2304B of the dead 4KB E slice
    asm volatile("s_waitcnt lgkmcnt(0)" ::: "memory");
    #pragma unroll
    for (int m = 0; m < 4; ++m)
        #pragma unroll
        for (int j = 0; j < 4; ++j)
            Tb[(8 * m + 4 * h + j) * 36 + c] = f2bf_rne(S[4 * m + j]);
    asm volatile("s_waitcnt lgkmcnt(0)" ::: "memory");
    u2v tg[4];
    #pragma unroll
    for (int g = 0; g < 4; ++g)
        tg[g] = *(const u2v*)(Tb + c * 36 + 8 * g + 4 * h);
    unsigned short* gm = (unsigned short*)ws + SH_MATS + (size_t)p * 1024 + l * 16;
    u4v s0; s0[0] = tg[0][0]; s0[1] = tg[0][1]; s0[2] = tg[1][0]; s0[3] = tg[1][1];
    u4v s1; s1[0] = tg[2][0]; s1[1] = tg[2][1]; s1[2] = tg[3][0]; s1[3] = tg[3][1];
    *(u4v*)(gm) = s0;
    *(u4v*)(gm + 8) = s1;
    if (l == 0) ws[WS_LS + p] = cacc + LN2F * l2acc;
}

// ---- helper: one product step  U <- A_mat * U  (A from 2 uint4 regs, A-frag order) ----
__device__ __forceinline__ f16v prodAU(const u4v a0, const u4v a1, const f16v U, const f16v zf) {
    s4v aA[4];
    u2v t;
    t[0] = a0[0]; t[1] = a0[1]; aA[0] = __builtin_bit_cast(s4v, t);
    t[0] = a0[2]; t[1] = a0[3]; aA[1] = __builtin_bit_cast(s4v, t);
    t[0] = a1[0]; t[1] = a1[1]; aA[2] = __builtin_bit_cast(s4v, t);
    t[0] = a1[2]; t[1] = a1[3]; aA[3] = __builtin_bit_cast(s4v, t);
    f16v Dv = zf;
    #pragma unroll
    for (int g = 0; g < 4; ++g) {
        i2v bd; bd[0] = pkbf(U[4 * g + 1], U[4 * g + 0]);
                bd[1] = pkbf(U[4 * g + 3], U[4 * g + 2]);
        Dv = __builtin_amdgcn_mfma_f32_32x32x8bf16_1k(aA[g], __builtin_bit_cast(s4v, bd), Dv, 0, 0, 0);
    }
    return Dv;
}

// ================= k2: combine 64 chunk mats per block (2 waves x 32 + pair) =================
__global__ __launch_bounds__(128, 1) void k2_combine(float* __restrict__ ws)
{
    __shared__ __align__(16) unsigned short slot[2][1152];  // row-major, stride 36
    __shared__ float scl[2], lac[2];
    const int tid = threadIdx.x, wv = tid >> 6, l = tid & 63, h = l >> 5, c = l & 31;
    const int blk = blockIdx.x;
    const int idx0 = blk * 64 + wv * 32;
    const unsigned short* mats = (const unsigned short*)ws + SH_MATS;

    float lsv = (l < 32) ? ws[WS_LS + idx0 + l] : 0.f;
    float lssum = wsum64(lsv);

    f16v zf;
    #pragma unroll
    for (int r = 0; r < 16; ++r) zf[r] = 0.f;
    f16v U;
    #pragma unroll
    for (int m = 0; m < 4; ++m)
        #pragma unroll
        for (int j = 0; j < 4; ++j)
            U[4 * m + j] = ((8 * m + 4 * h + j) == c) ? 1.f : 0.f;
    float l2a = 0.f;

    u4v pf[2][2];
    {
        const u4v* mp0 = (const u4v*)(mats + (size_t)idx0 * 1024) + l * 2;
        const u4v* mp1 = (const u4v*)(mats + (size_t)(idx0 + 1) * 1024) + l * 2;
        pf[0][0] = mp0[0]; pf[0][1] = mp0[1];
        pf[1][0] = mp1[0]; pf[1][1] = mp1[1];
    }
    for (int q = 0; q < 32; ++q) {
        const u4v a0 = pf[q & 1][0], a1 = pf[q & 1][1];
        if (q + 2 < 32) {
            const u4v* mp = (const u4v*)(mats + (size_t)(idx0 + q + 2) * 1024) + l * 2;
            pf[q & 1][0] = mp[0]; pf[q & 1][1] = mp[1];
        }
        f16v Dv = prodAU(a0, a1, U, zf);
        if ((q & 3) == 3) {
            float mx = Dv[0];
            #pragma unroll
            for (int r = 1; r < 16; ++r) mx = fmaxf(mx, Dv[r]);
            mx = wmax64(mx);
            const float inv = __fdividef(1.f, mx);
            #pragma unroll
            for (int r = 0; r < 16; ++r) U[r] = Dv[r] * inv;
            l2a += __log2f(mx);
        } else {
            U = Dv;
        }
    }
    #pragma unroll
    for (int m = 0; m < 4; ++m)
        #pragma unroll
        for (int j = 0; j < 4; ++j)
            slot[wv][(8 * m + 4 * h + j) * 36 + c] = f2bf_rne(U[4 * m + j]);
    if (l == 0) { scl[wv] = lssum; lac[wv] = l2a; }
    __syncthreads();

    if (wv == 0) {
        // P = P_hi(slot1) * P_lo(U regs)
        u4v a0, a1;
        {
            u2v t0 = *(const u2v*)(&slot[1][c * 36 + 0 + 4 * h]);
            u2v t1 = *(const u2v*)(&slot[1][c * 36 + 8 + 4 * h]);
            u2v t2 = *(const u2v*)(&slot[1][c * 36 + 16 + 4 * h]);
            u2v t3 = *(const u2v*)(&slot[1][c * 36 + 24 + 4 * h]);
            a0[0] = t0[0]; a0[1] = t0[1]; a0[2] = t1[0]; a0[3] = t1[1];
            a1[0] = t2[0]; a1[1] = t2[1]; a1[2] = t3[0]; a1[3] = t3[1];
        }
        f16v Dv = prodAU(a0, a1, U, zf);
        float mx = Dv[0];
        #pragma unroll
        for (int r = 1; r < 16; ++r) mx = fmaxf(mx, Dv[r]);
        mx = wmax64(mx);
        const float inv = __fdividef(1.f, mx);
        #pragma unroll
        for (int r = 0; r < 16; ++r) U[r] = Dv[r] * inv;
        const float l2tot = lac[0] + lac[1] + __log2f(mx);
        // transpose via slot[0] -> A-frag order global
        asm volatile("s_waitcnt lgkmcnt(0)" ::: "memory");
        #pragma unroll
        for (int m = 0; m < 4; ++m)
            #pragma unroll
            for (int j = 0; j < 4; ++j)
                slot[0][(8 * m + 4 * h + j) * 36 + c] = f2bf_rne(U[4 * m + j]);
        asm volatile("s_waitcnt lgkmcnt(0)" ::: "memory");
        u2v tg[4];
        #pragma unroll
        for (int g = 0; g < 4; ++g)
            tg[g] = *(const u2v*)(&slot[0][c * 36 + 8 * g + 4 * h]);
        unsigned short* gm = (unsigned short*)ws + SH_MATS2 + (size_t)blk * 1024 + l * 16;
        u4v s0; s0[0] = tg[0][0]; s0[1] = tg[0][1]; s0[2] = tg[1][0]; s0[3] = tg[1][1];
        u4v s1; s1[0] = tg[2][0]; s1[1] = tg[2][1]; s1[2] = tg[3][0]; s1[3] = tg[3][1];
        *(u4v*)(gm) = s0;
        *(u4v*)(gm + 8) = s1;
        if (l == 0) ws[WS_LS2 + blk] = scl[0] + scl[1] + LN2F * l2tot;
    }
}

// ================= k3: 16 chains of 8 + LDS tree + final loss =================
__global__ __launch_bounds__(1024, 1) void k3_final(
    const float* __restrict__ Y, const float* __restrict__ dTp,
    float* __restrict__ ws, float* __restrict__ out)
{
    __shared__ __align__(16) unsigned short slot[16][1152];
    __shared__ float sc[16];
    const int tid = threadIdx.x, wv = tid >> 6, l = tid & 63, h = l >> 5, c = l & 31;
    const unsigned short* mats2 = (const unsigned short*)ws + SH_MATS2;

    f16v zf;
    #pragma unroll
    for (int r = 0; r < 16; ++r) zf[r] = 0.f;

    // ---- phase A: each wave chains 8 group mats ----
    const int idx0 = wv * 8;
    float lsv = (l < 8) ? ws[WS_LS2 + idx0 + l] : 0.f;
    float lssum = wsum64(lsv);
    f16v U;
    #pragma unroll
    for (int m = 0; m < 4; ++m)
        #pragma unroll
        for (int j = 0; j < 4; ++j)
            U[4 * m + j] = ((8 * m + 4 * h + j) == c) ? 1.f : 0.f;
    float l2a = 0.f;
    u4v pf[2][2];
    {
        const u4v* mp0 = (const u4v*)(mats2 + (size_t)idx0 * 1024) + l * 2;
        const u4v* mp1 = (const u4v*)(mats2 + (size_t)(idx0 + 1) * 1024) + l * 2;
        pf[0][0] = mp0[0]; pf[0][1] = mp0[1];
        pf[1][0] = mp1[0]; pf[1][1] = mp1[1];
    }
    for (int q = 0; q < 8; ++q) {
        const u4v a0 = pf[q & 1][0], a1 = pf[q & 1][1];
        if (q + 2 < 8) {
            const u4v* mp = (const u4v*)(mats2 + (size_t)(idx0 + q + 2) * 1024) + l * 2;
            pf[q & 1][0] = mp[0]; pf[q & 1][1] = mp[1];
        }
        f16v Dv = prodAU(a0, a1, U, zf);
        if ((q & 3) == 3) {
            float mx = Dv[0];
            #pragma unroll
            for (int r = 1; r < 16; ++r) mx = fmaxf(mx, Dv[r]);
            mx = wmax64(mx);
            const float inv = __fdividef(1.f, mx);
            #pragma unroll
            for (int r = 0; r < 16; ++r) U[r] = Dv[r] * inv;
            l2a += __log2f(mx);
        } else {
            U = Dv;
        }
    }
    #pragma unroll
    for (int m = 0; m < 4; ++m)
        #pragma unroll
        for (int j = 0; j < 4; ++j)
            slot[wv][(8 * m + 4 * h + j) * 36 + c] = f2bf_rne(U[4 * m + j]);
    if (l == 0) sc[wv] = lssum + LN2F * l2a;
    __syncthreads();

    // ---- tree: 16 -> 1 ----
    for (int s = 1; s < 16; s <<= 1) {
        const int cnt = 16 / (2 * s);
        if (wv < cnt) {
            const int i = wv * 2 * s;
            s4v aA[4], bB[4];
            #pragma unroll
            for (int g = 0; g < 4; ++g) {
                u2v t = *(const u2v*)(&slot[i + s][c * 36 + 8 * g + 4 * h]);
                aA[g] = __builtin_bit_cast(s4v, t);
                s4v b;
                #pragma unroll
                for (int j = 0; j < 4; ++j)
                    b[j] = (short)slot[i][(8 * g + 4 * h + j) * 36 + c];
                bB[g] = b;
            }
            f16v Dv = zf;
            #pragma unroll
            for (int g = 0; g < 4; ++g)
                Dv = __builtin_amdgcn_mfma_f32_32x32x8bf16_1k(aA[g], bB[g], Dv, 0, 0, 0);
            float mx = Dv[0];
            #pragma unroll
            for (int r = 1; r < 16; ++r) mx = fmaxf(mx, Dv[r]);
            mx = wmax64(mx);
            const float inv = __fdividef(1.f, mx);
            #pragma unroll
            for (int m = 0; m < 4; ++m)
                #pragma unroll
                for (int j = 0; j < 4; ++j)
                    slot[i][(8 * m + 4 * h + j) * 36 + c] = f2bf_rne(Dv[4 * m + j] * inv);
            if (l == 0) sc[i] = sc[i] + sc[i + s] + __logf(mx);
        }
        __syncthreads();
    }

    // ---- final: a0 = exp-scaled(pi0 + ll0), loss = -(sc[0] + c0 + log(1^T P a0)) ----
    if (wv == 0) {
        float acc = 0.f;
        const float* Wf = ws + WS_WF;
        for (int dd = 0; dd < 128; ++dd) {
            const float yv = Y[dd & 63];
            const float f = (dd < 64) ? yv * yv : yv;
            acc = fmaf(f, Wf[dd * 32 + c], acc);
        }
        const float dt0 = dTp[0];
        const float ll0 = acc + ws[WS_CK + c] + ws[WS_AM1 + c] * __logf(dt0) - ws[WS_BB + c] * dt0;
        const float av = ws[WS_PI0 + c] + ll0;
        const float c0 = wmax32(av);
        const float a0 = __expf(av - c0);
        float part = 0.f;
        #pragma unroll
        for (int i = 0; i < 16; ++i) {
            const int ii = 16 * h + i;
            const float m = bf2f(slot[0][c * 36 + ii]);
            const float ai = __shfl(a0, ii);
            part = fmaf(m, ai, part);
        }
        const float srow = part + __shfl_xor(part, 32);
        const float tot = wsum32(srow);
        if (l == 0) out[(size_t)TT * DD] = -(sc[0] + c0 + __logf(tot));
    }
}

// ================= launcher =================
extern "C" void kernel_launch(void* const* d_in, const int* in_sizes, int n_in,
                              void* d_out, int out_size, void* d_ws, size_t ws_size,
                              hipStream_t stream)
{
    const float* Y   = (const float*)d_in[0];
    const float* dTp = (const float*)d_in[1];
    const float* A   = (const float*)d_in[2];
    const float* lab = (const float*)d_in[3];
    const float* mu  = (const float*)d_in[4];
    const float* lsg = (const float*)d_in[5];
    const float* pi  = (const float*)d_in[6];
    float* out = (float*)d_out;
    float* ws  = (float*)d_ws;

    hipLaunchKernelGGL(k0_prep, dim3(1), dim3(256), 0, stream, Y, A, lab, mu, lsg, pi, ws, out);
    hipLaunchKernelGGL(k1_scan, dim3(PCH / 4), dim3(256), 0, stream, Y, dTp, ws, out);
    hipLaunchKernelGGL(k2_combine, dim3(128), dim3(128), 0, stream, ws);
    hipLaunchKernelGGL(k3_final, dim3(1), dim3(1024), 0, stream, Y, dTp, ws, out);
}

// Round 3
// 189.147 us; speedup vs baseline: 1.3874x; 1.1300x over previous
//
#include <hip/hip_runtime.h>
#include <stdint.h>

// ---------------- problem constants ----------------
#define TT 262144
#define KK 32
#define DD 64
#define LSTEP 32               // scan steps per chunk
#define PCH 8192               // chunks (transitions t=1..T-1; last chunk has 31 steps)
#define YSTRIDE 68             // padded LDS row stride (floats)

typedef __attribute__((ext_vector_type(4)))  float f4v;
typedef __attribute__((ext_vector_type(16))) float f16v;
typedef __attribute__((ext_vector_type(4)))  short s4v;
typedef __attribute__((ext_vector_type(2)))  int   i2v;
typedef __attribute__((ext_vector_type(2)))  unsigned int u2v;
typedef __attribute__((ext_vector_type(4)))  unsigned int u4v;

// ---------------- ws layout ----------------
// ushort-unit offsets (prep region)
#define WS_AFRAG_US 0          // ushort[1024] : Anorm^T A-frags [g:4][lane:64][e:4]
#define WS_WFRAG_US 1024       // ushort[4096] : W B-frags      [s:16][lane:64][e:4]
// float-unit offsets
#define WS_WF    2560          // float[4096]  : W fp32 [dd:128][k:32] (for k3 ll0)
#define WS_CK    6656          // float[32]
#define WS_AM1   6688          // float[32]
#define WS_BB    6720          // float[32]
#define WS_PI0   6752          // float[32]
#define WS_LS    8192          // float[PCH]   : chunk log-scales
#define WS_LS2   16384         // float[128]   : group log-scales
// short-unit offsets (matrix storage, bf16)
#define SH_MATS  33280                  // ushort[PCH*1024]  : chunk mats, A-frag order
#define SH_MATS2 (33280 + PCH*1024)     // ushort[128*1024]  : group mats, A-frag order
#define LN2F 0.69314718055994531f

__device__ __forceinline__ unsigned pkbf(float hi, float lo) {
    return __builtin_amdgcn_perm(__builtin_bit_cast(unsigned, hi),
                                 __builtin_bit_cast(unsigned, lo), 0x07060302u);
}
__device__ __forceinline__ unsigned short f2bf_rne(float f) {
    unsigned u = __builtin_bit_cast(unsigned, f);
    unsigned r = u + 0x7FFFu + ((u >> 16) & 1u);
    return (unsigned short)(r >> 16);
}
__device__ __forceinline__ float bf2f(unsigned short u) {
    return __builtin_bit_cast(float, (unsigned)u << 16);
}
__device__ __forceinline__ float wmax32(float v) {
    v = fmaxf(v, __shfl_xor(v, 1));  v = fmaxf(v, __shfl_xor(v, 2));
    v = fmaxf(v, __shfl_xor(v, 4));  v = fmaxf(v, __shfl_xor(v, 8));
    v = fmaxf(v, __shfl_xor(v, 16));
    return v;
}
__device__ __forceinline__ float wmax64(float v) {
    v = wmax32(v); v = fmaxf(v, __shfl_xor(v, 32));
    return v;
}
__device__ __forceinline__ float wsum32(float v) {
    v += __shfl_xor(v, 1); v += __shfl_xor(v, 2); v += __shfl_xor(v, 4);
    v += __shfl_xor(v, 8); v += __shfl_xor(v, 16);
    return v;
}
__device__ __forceinline__ float wsum64(float v) {
    v = wsum32(v); v += __shfl_xor(v, 32);
    return v;
}
__device__ __forceinline__ float wval(int dd, int k, const float* mu, const float* lsg) {
    int d = dd & 63;
    float lv = lsg[k * DD + d];
    float iv = __expf(-2.f * lv);
    return (dd < DD) ? (-0.5f * iv) : (mu[k * DD + d] * iv);
}

// ================= k0: constants / fragment preformat =================
__global__ void k0_prep(const float* __restrict__ Y, const float* __restrict__ A,
                        const float* __restrict__ lab, const float* __restrict__ mu,
                        const float* __restrict__ lsg, const float* __restrict__ pi,
                        float* __restrict__ ws, float* __restrict__ out)
{
    __shared__ float lseA[KK];
    const int tid = threadIdx.x;
    if (tid < KK) {
        float m = -1e30f;
        for (int j = 0; j < KK; ++j) m = fmaxf(m, A[tid * KK + j]);
        float s = 0.f;
        for (int j = 0; j < KK; ++j) s += __expf(A[tid * KK + j] - m);
        lseA[tid] = m + __logf(s);

        float mp = -1e30f;
        for (int j = 0; j < KK; ++j) mp = fmaxf(mp, pi[j]);
        float sp = 0.f;
        for (int j = 0; j < KK; ++j) sp += __expf(pi[j] - mp);
        ws[WS_PI0 + tid] = pi[tid] - (mp + __logf(sp));

        float la = lab[tid * 2 + 0], lb = lab[tid * 2 + 1];
        float a = __expf(la), b = __expf(lb);
        float c1 = 0.f, c2 = 0.f;
        for (int d = 0; d < DD; ++d) {
            float lv = lsg[tid * DD + d];
            float mv = mu[tid * DD + d];
            c1 -= lv;
            c2 += mv * mv * __expf(-2.f * lv);
        }
        ws[WS_CK + tid]  = a * lb - lgammaf(a) + c1 - 0.5f * c2 - 32.f * 1.8378770664093453f;
        ws[WS_AM1 + tid] = a - 1.f;
        ws[WS_BB + tid]  = b;
    }
    __syncthreads();
    unsigned short* us = (unsigned short*)ws;
    for (int idx = tid; idx < 1024; idx += 256) {
        int g = idx >> 8, rem = idx & 255, ln = rem >> 2, e = rem & 3;
        int m = 8 * g + 4 * (ln >> 5) + e, i = ln & 31;
        us[WS_AFRAG_US + idx] = f2bf_rne(__expf(A[m * KK + i] - lseA[m]));
    }
    for (int idx = tid; idx < 4096; idx += 256) {
        int s = idx >> 8, rem = idx & 255, ln = rem >> 2, e = rem & 3;
        int dd = 8 * s + 4 * (ln >> 5) + e, k = ln & 31;
        us[WS_WFRAG_US + idx] = f2bf_rne(wval(dd, k, mu, lsg));
    }
    for (int idx = tid; idx < 4096; idx += 256) {
        int dd = idx >> 5, k = idx & 31;
        ws[WS_WF + idx] = wval(dd, k, mu, lsg);
    }
    if (tid < DD) out[tid] = Y[tid];   // h row 0
}

// ================= k1: chunk scan (1 wave = 1 chunk of 32 steps) =================
// All global traffic coalesced: Y staged through LDS (1KB/instr), h written from
// the staging registers (1KB/instr), mats stored 16B/lane contiguous.
__global__ __launch_bounds__(256, 4) void k1_scan(
    const float* __restrict__ Y, const float* __restrict__ dTp,
    float* __restrict__ ws, float* __restrict__ out)
{
    __shared__ __align__(16) float Yt[4][32 * YSTRIDE];  // 8704B/wave; E + transpose buf alias here
    __shared__ __align__(16) float dtv[4][32], dtl[4][32];

    const int tid = threadIdx.x;
    const int wv = tid >> 6, l = tid & 63, h = l >> 5, c = l & 31;
    const int p = blockIdx.x * 4 + wv;
    const int t0 = 1 + p * LSTEP;
    const int nsteps = min(LSTEP, TT - t0);

    const unsigned short* afr = (const unsigned short*)ws + WS_AFRAG_US;
    const unsigned short* wfr = (const unsigned short*)ws + WS_WFRAG_US;

    const float cK = ws[WS_CK + c], am1 = ws[WS_AM1 + c], bb = ws[WS_BB + c];

    if (l < 32) {
        int t = t0 + l;
        float dv = (t < TT) ? dTp[t] : 1.f;
        dtv[wv][l] = dv;
        dtl[wv][l] = __logf(dv);
    }

    f16v zf;
    #pragma unroll
    for (int r = 0; r < 16; ++r) zf[r] = 0.f;

    // ---- coalesced Y stage -> LDS, fused coalesced h write ----
    {
        const size_t gbase = (size_t)t0 * DD;
        const int r = (l >> 4);            // sub-row within 4-row group
        const int col = (l & 15) * 4;
        #pragma unroll
        for (int i = 0; i < 8; ++i) {
            const size_t gi = gbase + (size_t)i * 256 + l * 4;
            f4v y4; y4[0] = 0.f; y4[1] = 0.f; y4[2] = 0.f; y4[3] = 0.f;
            const bool ok = gi < (size_t)TT * DD;
            if (ok) y4 = *(const f4v*)(Y + gi);
            if (ok) *(f4v*)(out + gi) = y4;
            *(f4v*)(&Yt[wv][(i * 4 + r) * YSTRIDE + col]) = y4;
        }
    }

    // ---- emission ll tile via MFMA (frags from LDS) ----
    f16v acc = zf;
    s4v rawf[8];
    #pragma unroll
    for (int g = 0; g < 8; ++g) {
        const f4v y4 = *(const f4v*)(&Yt[wv][c * YSTRIDE + 8 * g + 4 * h]);
        const f4v q4 = y4 * y4;
        i2v sq; sq[0] = pkbf(q4[1], q4[0]); sq[1] = pkbf(q4[3], q4[2]);
        i2v rw; rw[0] = pkbf(y4[1], y4[0]); rw[1] = pkbf(y4[3], y4[2]);
        rawf[g] = __builtin_bit_cast(s4v, rw);
        s4v wf = *(const s4v*)(wfr + g * 256 + l * 4);
        acc = __builtin_amdgcn_mfma_f32_32x32x8bf16_1k(__builtin_bit_cast(s4v, sq), wf, acc, 0, 0, 0);
    }
    #pragma unroll
    for (int g = 0; g < 8; ++g) {
        s4v wf = *(const s4v*)(wfr + (8 + g) * 256 + l * 4);
        acc = __builtin_amdgcn_mfma_f32_32x32x8bf16_1k(rawf[g], wf, acc, 0, 0, 0);
    }

    s4v aF[4];
    #pragma unroll
    for (int g = 0; g < 4; ++g) aF[g] = *(const s4v*)(afr + g * 256 + l * 4);

    // ---- ll -> c_t (row max over states), e = exp(ll-c) into E (aliases Yt cols 0..31) ----
    float csv = 0.f;
    #pragma unroll
    for (int m = 0; m < 4; ++m) {
        const f4v dv4 = *(const f4v*)(&dtv[wv][8 * m + 4 * h]);
        const f4v dl4 = *(const f4v*)(&dtl[wv][8 * m + 4 * h]);
        #pragma unroll
        for (int j = 0; j < 4; ++j) {
            const int row = 8 * m + 4 * h + j;
            float llv = acc[4 * m + j] + cK + am1 * dl4[j] - bb * dv4[j];
            float cm = wmax32(llv);
            Yt[wv][row * YSTRIDE + c] = __expf(llv - cm);
            csv += (row < nsteps) ? cm : 0.f;
        }
    }
    float cacc = wsum64(csv) * (1.f / 32.f);

    asm volatile("s_waitcnt lgkmcnt(0)" ::: "memory");  // E visible to own wave

    // ---- scan: S <- diag(e_t) * Anorm^T * S ----
    f16v S;
    #pragma unroll
    for (int m = 0; m < 4; ++m)
        #pragma unroll
        for (int j = 0; j < 4; ++j)
            S[4 * m + j] = ((8 * m + 4 * h + j) == c) ? 1.f : 0.f;
    float l2acc = 0.f;

    auto step = [&](int n) {
        f16v Dv = zf;
        #pragma unroll
        for (int g = 0; g < 4; ++g) {
            i2v bd; bd[0] = pkbf(S[4 * g + 1], S[4 * g + 0]);
                    bd[1] = pkbf(S[4 * g + 3], S[4 * g + 2]);
            Dv = __builtin_amdgcn_mfma_f32_32x32x8bf16_1k(aF[g], __builtin_bit_cast(s4v, bd), Dv, 0, 0, 0);
        }
        #pragma unroll
        for (int m = 0; m < 4; ++m) {
            const f4v e4 = *(const f4v*)(&Yt[wv][n * YSTRIDE + 8 * m + 4 * h]);
            #pragma unroll
            for (int j = 0; j < 4; ++j) S[4 * m + j] = Dv[4 * m + j] * e4[j];
        }
    };
    auto rescale = [&]() {
        float mx = S[0];
        #pragma unroll
        for (int r = 1; r < 16; ++r) mx = fmaxf(mx, S[r]);
        mx = wmax64(mx);
        const float inv = __fdividef(1.f, mx);
        #pragma unroll
        for (int r = 0; r < 16; ++r) S[r] *= inv;
        l2acc += __log2f(mx);
    };

    if (p != PCH - 1) {
        #pragma unroll
        for (int n = 0; n < LSTEP; ++n) {
            step(n);
            if ((n & 3) == 3) rescale();
        }
    } else {
        for (int n = 0; n < nsteps; ++n) {
            step(n);
            if ((n & 3) == 3) rescale();
        }
    }

    // ---- transpose S (C-layout) -> A-frag order bf16, coalesced store ----
    unsigned short* Tb = (unsigned short*)&Yt[wv][0];    // Yt slice is dead now
    asm volatile("s_waitcnt lgkmcnt(0)" ::: "memory");
    #pragma unroll
    for (int m = 0; m < 4; ++m)
        #pragma unroll
        for (int j = 0; j < 4; ++j)
            Tb[(8 * m + 4 * h + j) * 36 + c] = f2bf_rne(S[4 * m + j]);
    asm volatile("s_waitcnt lgkmcnt(0)" ::: "memory");
    u2v tg[4];
    #pragma unroll
    for (int g = 0; g < 4; ++g)
        tg[g] = *(const u2v*)(Tb + c * 36 + 8 * g + 4 * h);
    unsigned short* gm = (unsigned short*)ws + SH_MATS + (size_t)p * 1024 + l * 16;
    u4v s0; s0[0] = tg[0][0]; s0[1] = tg[0][1]; s0[2] = tg[1][0]; s0[3] = tg[1][1];
    u4v s1; s1[0] = tg[2][0]; s1[1] = tg[2][1]; s1[2] = tg[3][0]; s1[3] = tg[3][1];
    *(u4v*)(gm) = s0;
    *(u4v*)(gm + 8) = s1;
    if (l == 0) ws[WS_LS + p] = cacc + LN2F * l2acc;
}

// ---- helper: one product step  U <- A_mat * U  (A from 2 uint4 regs, A-frag order) ----
__device__ __forceinline__ f16v prodAU(const u4v a0, const u4v a1, const f16v U, const f16v zf) {
    s4v aA[4];
    u2v t;
    t[0] = a0[0]; t[1] = a0[1]; aA[0] = __builtin_bit_cast(s4v, t);
    t[0] = a0[2]; t[1] = a0[3]; aA[1] = __builtin_bit_cast(s4v, t);
    t[0] = a1[0]; t[1] = a1[1]; aA[2] = __builtin_bit_cast(s4v, t);
    t[0] = a1[2]; t[1] = a1[3]; aA[3] = __builtin_bit_cast(s4v, t);
    f16v Dv = zf;
    #pragma unroll
    for (int g = 0; g < 4; ++g) {
        i2v bd; bd[0] = pkbf(U[4 * g + 1], U[4 * g + 0]);
                bd[1] = pkbf(U[4 * g + 3], U[4 * g + 2]);
        Dv = __builtin_amdgcn_mfma_f32_32x32x8bf16_1k(aA[g], __builtin_bit_cast(s4v, bd), Dv, 0, 0, 0);
    }
    return Dv;
}

// ================= k2: combine 64 chunk mats per block (2 waves x 32 + pair) =================
__global__ __launch_bounds__(128, 1) void k2_combine(float* __restrict__ ws)
{
    __shared__ __align__(16) unsigned short slot[2][1152];  // row-major, stride 36
    __shared__ float scl[2], lac[2];
    const int tid = threadIdx.x, wv = tid >> 6, l = tid & 63, h = l >> 5, c = l & 31;
    const int blk = blockIdx.x;
    const int idx0 = blk * 64 + wv * 32;
    const unsigned short* mats = (const unsigned short*)ws + SH_MATS;

    float lsv = (l < 32) ? ws[WS_LS + idx0 + l] : 0.f;
    float lssum = wsum64(lsv);

    f16v zf;
    #pragma unroll
    for (int r = 0; r < 16; ++r) zf[r] = 0.f;
    f16v U;
    #pragma unroll
    for (int m = 0; m < 4; ++m)
        #pragma unroll
        for (int j = 0; j < 4; ++j)
            U[4 * m + j] = ((8 * m + 4 * h + j) == c) ? 1.f : 0.f;
    float l2a = 0.f;

    u4v pf[2][2];
    {
        const u4v* mp0 = (const u4v*)(mats + (size_t)idx0 * 1024) + l * 2;
        const u4v* mp1 = (const u4v*)(mats + (size_t)(idx0 + 1) * 1024) + l * 2;
        pf[0][0] = mp0[0]; pf[0][1] = mp0[1];
        pf[1][0] = mp1[0]; pf[1][1] = mp1[1];
    }
    for (int q = 0; q < 32; ++q) {
        const u4v a0 = pf[q & 1][0], a1 = pf[q & 1][1];
        if (q + 2 < 32) {
            const u4v* mp = (const u4v*)(mats + (size_t)(idx0 + q + 2) * 1024) + l * 2;
            pf[q & 1][0] = mp[0]; pf[q & 1][1] = mp[1];
        }
        f16v Dv = prodAU(a0, a1, U, zf);
        if ((q & 3) == 3) {
            float mx = Dv[0];
            #pragma unroll
            for (int r = 1; r < 16; ++r) mx = fmaxf(mx, Dv[r]);
            mx = wmax64(mx);
            const float inv = __fdividef(1.f, mx);
            #pragma unroll
            for (int r = 0; r < 16; ++r) U[r] = Dv[r] * inv;
            l2a += __log2f(mx);
        } else {
            U = Dv;
        }
    }
    #pragma unroll
    for (int m = 0; m < 4; ++m)
        #pragma unroll
        for (int j = 0; j < 4; ++j)
            slot[wv][(8 * m + 4 * h + j) * 36 + c] = f2bf_rne(U[4 * m + j]);
    if (l == 0) { scl[wv] = lssum; lac[wv] = l2a; }
    __syncthreads();

    if (wv == 0) {
        u4v a0, a1;
        {
            u2v t0 = *(const u2v*)(&slot[1][c * 36 + 0 + 4 * h]);
            u2v t1 = *(const u2v*)(&slot[1][c * 36 + 8 + 4 * h]);
            u2v t2 = *(const u2v*)(&slot[1][c * 36 + 16 + 4 * h]);
            u2v t3 = *(const u2v*)(&slot[1][c * 36 + 24 + 4 * h]);
            a0[0] = t0[0]; a0[1] = t0[1]; a0[2] = t1[0]; a0[3] = t1[1];
            a1[0] = t2[0]; a1[1] = t2[1]; a1[2] = t3[0]; a1[3] = t3[1];
        }
        f16v Dv = prodAU(a0, a1, U, zf);
        float mx = Dv[0];
        #pragma unroll
        for (int r = 1; r < 16; ++r) mx = fmaxf(mx, Dv[r]);
        mx = wmax64(mx);
        const float inv = __fdividef(1.f, mx);
        #pragma unroll
        for (int r = 0; r < 16; ++r) U[r] = Dv[r] * inv;
        const float l2tot = lac[0] + lac[1] + __log2f(mx);
        asm volatile("s_waitcnt lgkmcnt(0)" ::: "memory");
        #pragma unroll
        for (int m = 0; m < 4; ++m)
            #pragma unroll
            for (int j = 0; j < 4; ++j)
                slot[0][(8 * m + 4 * h + j) * 36 + c] = f2bf_rne(U[4 * m + j]);
        asm volatile("s_waitcnt lgkmcnt(0)" ::: "memory");
        u2v tg[4];
        #pragma unroll
        for (int g = 0; g < 4; ++g)
            tg[g] = *(const u2v*)(&slot[0][c * 36 + 8 * g + 4 * h]);
        unsigned short* gm = (unsigned short*)ws + SH_MATS2 + (size_t)blk * 1024 + l * 16;
        u4v s0; s0[0] = tg[0][0]; s0[1] = tg[0][1]; s0[2] = tg[1][0]; s0[3] = tg[1][1];
        u4v s1; s1[0] = tg[2][0]; s1[1] = tg[2][1]; s1[2] = tg[3][0]; s1[3] = tg[3][1];
        *(u4v*)(gm) = s0;
        *(u4v*)(gm + 8) = s1;
        if (l == 0) ws[WS_LS2 + blk] = scl[0] + scl[1] + LN2F * l2tot;
    }
}

// ================= k3: 16 chains of 8 + LDS tree + final loss =================
__global__ __launch_bounds__(1024, 1) void k3_final(
    const float* __restrict__ Y, const float* __restrict__ dTp,
    float* __restrict__ ws, float* __restrict__ out)
{
    __shared__ __align__(16) unsigned short slot[16][1152];
    __shared__ float sc[16];
    const int tid = threadIdx.x, wv = tid >> 6, l = tid & 63, h = l >> 5, c = l & 31;
    const unsigned short* mats2 = (const unsigned short*)ws + SH_MATS2;

    f16v zf;
    #pragma unroll
    for (int r = 0; r < 16; ++r) zf[r] = 0.f;

    const int idx0 = wv * 8;
    float lsv = (l < 8) ? ws[WS_LS2 + idx0 + l] : 0.f;
    float lssum = wsum64(lsv);
    f16v U;
    #pragma unroll
    for (int m = 0; m < 4; ++m)
        #pragma unroll
        for (int j = 0; j < 4; ++j)
            U[4 * m + j] = ((8 * m + 4 * h + j) == c) ? 1.f : 0.f;
    float l2a = 0.f;
    u4v pf[2][2];
    {
        const u4v* mp0 = (const u4v*)(mats2 + (size_t)idx0 * 1024) + l * 2;
        const u4v* mp1 = (const u4v*)(mats2 + (size_t)(idx0 + 1) * 1024) + l * 2;
        pf[0][0] = mp0[0]; pf[0][1] = mp0[1];
        pf[1][0] = mp1[0]; pf[1][1] = mp1[1];
    }
    for (int q = 0; q < 8; ++q) {
        const u4v a0 = pf[q & 1][0], a1 = pf[q & 1][1];
        if (q + 2 < 8) {
            const u4v* mp = (const u4v*)(mats2 + (size_t)(idx0 + q + 2) * 1024) + l * 2;
            pf[q & 1][0] = mp[0]; pf[q & 1][1] = mp[1];
        }
        f16v Dv = prodAU(a0, a1, U, zf);
        if ((q & 3) == 3) {
            float mx = Dv[0];
            #pragma unroll
            for (int r = 1; r < 16; ++r) mx = fmaxf(mx, Dv[r]);
            mx = wmax64(mx);
            const float inv = __fdividef(1.f, mx);
            #pragma unroll
            for (int r = 0; r < 16; ++r) U[r] = Dv[r] * inv;
            l2a += __log2f(mx);
        } else {
            U = Dv;
        }
    }
    #pragma unroll
    for (int m = 0; m < 4; ++m)
        #pragma unroll
        for (int j = 0; j < 4; ++j)
            slot[wv][(8 * m + 4 * h + j) * 36 + c] = f2bf_rne(U[4 * m + j]);
    if (l == 0) sc[wv] = lssum + LN2F * l2a;
    __syncthreads();

    for (int s = 1; s < 16; s <<= 1) {
        const int cnt = 16 / (2 * s);
        if (wv < cnt) {
            const int i = wv * 2 * s;
            s4v aA[4], bB[4];
            #pragma unroll
            for (int g = 0; g < 4; ++g) {
                u2v t = *(const u2v*)(&slot[i + s][c * 36 + 8 * g + 4 * h]);
                aA[g] = __builtin_bit_cast(s4v, t);
                s4v b;
                #pragma unroll
                for (int j = 0; j < 4; ++j)
                    b[j] = (short)slot[i][(8 * g + 4 * h + j) * 36 + c];
                bB[g] = b;
            }
            f16v Dv = zf;
            #pragma unroll
            for (int g = 0; g < 4; ++g)
                Dv = __builtin_amdgcn_mfma_f32_32x32x8bf16_1k(aA[g], bB[g], Dv, 0, 0, 0);
            float mx = Dv[0];
            #pragma unroll
            for (int r = 1; r < 16; ++r) mx = fmaxf(mx, Dv[r]);
            mx = wmax64(mx);
            const float inv = __fdividef(1.f, mx);
            #pragma unroll
            for (int m = 0; m < 4; ++m)
                #pragma unroll
                for (int j = 0; j < 4; ++j)
                    slot[i][(8 * m + 4 * h + j) * 36 + c] = f2bf_rne(Dv[4 * m + j] * inv);
            if (l == 0) sc[i] = sc[i] + sc[i + s] + __logf(mx);
        }
        __syncthreads();
    }

    if (wv == 0) {
        float acc = 0.f;
        const float* Wf = ws + WS_WF;
        for (int dd = 0; dd < 128; ++dd) {
            const float yv = Y[dd & 63];
            const float f = (dd < 64) ? yv * yv : yv;
            acc = fmaf(f, Wf[dd * 32 + c], acc);
        }
        const float dt0 = dTp[0];
        const float ll0 = acc + ws[WS_CK + c] + ws[WS_AM1 + c] * __logf(dt0) - ws[WS_BB + c] * dt0;
        const float av = ws[WS_PI0 + c] + ll0;
        const float c0 = wmax32(av);
        const float a0 = __expf(av - c0);
        float part = 0.f;
        #pragma unroll
        for (int i = 0; i < 16; ++i) {
            const int ii = 16 * h + i;
            const float m = bf2f(slot[0][c * 36 + ii]);
            const float ai = __shfl(a0, ii);
            part = fmaf(m, ai, part);
        }
        const float srow = part + __shfl_xor(part, 32);
        const float tot = wsum32(srow);
        if (l == 0) out[(size_t)TT * DD] = -(sc[0] + c0 + __logf(tot));
    }
}

// ================= launcher =================
extern "C" void kernel_launch(void* const* d_in, const int* in_sizes, int n_in,
                              void* d_out, int out_size, void* d_ws, size_t ws_size,
                              hipStream_t stream)
{
    const float* Y   = (const float*)d_in[0];
    const float* dTp = (const float*)d_in[1];
    const float* A   = (const float*)d_in[2];
    const float* lab = (const float*)d_in[3];
    const float* mu  = (const float*)d_in[4];
    const float* lsg = (const float*)d_in[5];
    const float* pi  = (const float*)d_in[6];
    float* out = (float*)d_out;
    float* ws  = (float*)d_ws;

    hipLaunchKernelGGL(k0_prep, dim3(1), dim3(256), 0, stream, Y, A, lab, mu, lsg, pi, ws, out);
    hipLaunchKernelGGL(k1_scan, dim3(PCH / 4), dim3(256), 0, stream, Y, dTp, ws, out);
    hipLaunchKernelGGL(k2_combine, dim3(128), dim3(128), 0, stream, ws);
    hipLaunchKernelGGL(k3_final, dim3(1), dim3(1024), 0, stream, Y, dTp, ws, out);
}